// Round 9
// baseline (3917.577 us; speedup 1.0000x reference)
//
#include <hip/hip_runtime.h>
#include <math.h>

typedef __bf16 bf16_t;
typedef __bf16 bf16x8 __attribute__((ext_vector_type(8)));
typedef float f32x4 __attribute__((ext_vector_type(4)));
typedef int i32x4 __attribute__((ext_vector_type(4)));
typedef unsigned int u32;

#define HID 2048
#define NBATCH 16
#define SEQLEN 512
#define MTOT (NBATCH * SEQLEN)
#define NBLK 32
#define RTHREADS 512
#define LN_EPS 1e-5f
#define CHB 8                      // batches per chain

// ================= GEMM: inp = x @ Wi^T + b  -> d_out (fp32) =================
__global__ __launch_bounds__(256) void gemm_proj(
    const float* __restrict__ X,
    const float* __restrict__ Wi,
    const float* __restrict__ bias,
    float* __restrict__ C,
    int* __restrict__ flags)
{
    __shared__ bf16_t lA[128 * 32];
    __shared__ bf16_t lB[128 * 32];
    const int tid = threadIdx.x;
    if (blockIdx.x == 0 && blockIdx.y == 0) {
        if (tid < 128) flags[tid] = 0;   // both chains' flags; re-zero EVERY launch
    }
    const int lane = tid & 63;
    const int wv = tid >> 6;
    const int bn = blockIdx.x * 128;
    const int bm = blockIdx.y * 128;
    const int wr = (wv >> 1) * 64;
    const int wc = (wv & 1) * 64;

    f32x4 zero = {0.f, 0.f, 0.f, 0.f};
    f32x4 acc[4][4];
#pragma unroll
    for (int i = 0; i < 4; ++i)
#pragma unroll
        for (int j = 0; j < 4; ++j) acc[i][j] = zero;

    for (int k0 = 0; k0 < HID; k0 += 32) {
        __syncthreads();
#pragma unroll
        for (int c = 0; c < 2; ++c) {
            const int chunk = c * 256 + tid;      // 0..511
            const int row = chunk >> 2;           // 0..127
            const int kp = (chunk & 3) ^ (row & 3); // XOR-swizzled source chunk
            {
                const float* s = X + (size_t)(bm + row) * HID + k0 + kp * 8;
                float4 a0 = *(const float4*)s;
                float4 a1 = *(const float4*)(s + 4);
                bf16x8 v;
                v[0] = (bf16_t)a0.x; v[1] = (bf16_t)a0.y; v[2] = (bf16_t)a0.z; v[3] = (bf16_t)a0.w;
                v[4] = (bf16_t)a1.x; v[5] = (bf16_t)a1.y; v[6] = (bf16_t)a1.z; v[7] = (bf16_t)a1.w;
                *(bf16x8*)(lA + chunk * 8) = v;
            }
            {
                const float* s = Wi + (size_t)(bn + row) * HID + k0 + kp * 8;
                float4 a0 = *(const float4*)s;
                float4 a1 = *(const float4*)(s + 4);
                bf16x8 v;
                v[0] = (bf16_t)a0.x; v[1] = (bf16_t)a0.y; v[2] = (bf16_t)a0.z; v[3] = (bf16_t)a0.w;
                v[4] = (bf16_t)a1.x; v[5] = (bf16_t)a1.y; v[6] = (bf16_t)a1.z; v[7] = (bf16_t)a1.w;
                *(bf16x8*)(lB + chunk * 8) = v;
            }
        }
        __syncthreads();

        bf16x8 af[4], bfr[4];
#pragma unroll
        for (int i = 0; i < 4; ++i) {
            const int row = wr + i * 16 + (lane & 15);
            const int ck = (lane >> 4) ^ (row & 3);
            af[i] = *(const bf16x8*)(lA + row * 32 + ck * 8);
        }
#pragma unroll
        for (int j = 0; j < 4; ++j) {
            const int row = wc + j * 16 + (lane & 15);
            const int ck = (lane >> 4) ^ (row & 3);
            bfr[j] = *(const bf16x8*)(lB + row * 32 + ck * 8);
        }
#pragma unroll
        for (int i = 0; i < 4; ++i)
#pragma unroll
            for (int j = 0; j < 4; ++j)
                acc[i][j] = __builtin_amdgcn_mfma_f32_16x16x32_bf16(af[i], bfr[j], acc[i][j], 0, 0, 0);
    }

#pragma unroll
    for (int j = 0; j < 4; ++j) {
        const int col = bn + wc + j * 16 + (lane & 15);
        const float bv = bias[col];
#pragma unroll
        for (int i = 0; i < 4; ++i) {
#pragma unroll
            for (int r = 0; r < 4; ++r) {
                const int row = bm + wr + i * 16 + (lane >> 4) * 4 + r;
                C[(size_t)row * HID + col] = acc[i][j][r] + bv;
            }
        }
    }
}

// ================= Persistent recurrent kernel =================
// DUAL-CHAIN: batches 0-7 (chain A) and 8-15 (chain B) are mathematically
// independent recurrences. Both chains live on the same 32 blocks sharing the
// VGPR-resident weights; phases alternate A,B. While chain A's publish
// propagates through L3 (~2.5us), the block computes chain B's step -> the
// serial sync latency hides under the other chain's compute.
// Per-chain protocol = R8's validated one: flags[32] (A) / flags[64..95] (B);
// per-wave vmcnt(0) drain -> barrier T -> tid0 publishes t+1; wave0 polls.
// MFMA uses 8 of 16 A-rows (lane&7 duplicates; dup outputs discarded).
__global__ __launch_bounds__(RTHREADS, 1) void recurrent(
    const float* __restrict__ Wr,
    const float* __restrict__ mask,
    const float* __restrict__ tau,
    float* __restrict__ io,      // d_out: holds inp (read rows t+1) -> states (write row t)
    bf16_t* __restrict__ stA0,
    bf16_t* __restrict__ stA1,
    bf16_t* __restrict__ stB0,
    bf16_t* __restrict__ stB1,
    int* __restrict__ flags)     // [0..31]=A, [64..95]=B
{
    const int tid = threadIdx.x;
    const int lane = tid & 63;
    const int wv = tid >> 6;          // K-eighth 0..7 (also update row)
    const int colbase = blockIdx.x * 64;

    __shared__ float red[8][8][68];   // [kq][batchrow][col]

    // ---- preload masked weights: 32 MFMA B-fragments per wave ----
    bf16x8 wf[32];
    {
        const int kb = wv * 256 + (lane >> 4) * 8;
#pragma unroll
        for (int ct = 0; ct < 4; ++ct) {
            const int gc = colbase + ct * 16 + (lane & 15);
#pragma unroll
            for (int kf = 0; kf < 8; ++kf) {
                const size_t off = (size_t)gc * HID + kb + kf * 32;
                float4 a0 = *(const float4*)(Wr + off);
                float4 a1 = *(const float4*)(Wr + off + 4);
                float4 m0 = *(const float4*)(mask + off);
                float4 m1 = *(const float4*)(mask + off + 4);
                bf16x8 v;
                v[0] = (bf16_t)(a0.x * m0.x); v[1] = (bf16_t)(a0.y * m0.y);
                v[2] = (bf16_t)(a0.z * m0.z); v[3] = (bf16_t)(a0.w * m0.w);
                v[4] = (bf16_t)(a1.x * m1.x); v[5] = (bf16_t)(a1.y * m1.y);
                v[6] = (bf16_t)(a1.z * m1.z); v[7] = (bf16_t)(a1.w * m1.w);
                wf[ct * 8 + kf] = v;
            }
        }
    }

    // update mapping: thread = (batchrow urow = wv, col ucol = lane)
    const int urow = wv;
    const int ucol = lane;
    const int gcol = colbase + ucol;
    const size_t SH = (size_t)SEQLEN * HID;
    float al;
    {
        float tv = fminf(fmaxf(tau[gcol], 1.0f), 20.0f);
        al = fminf(fmaxf(0.5f / tv, 0.0f), 1.0f);
    }

    float s_oldA = 0.f, s_oldB = 0.f;
    float cinA = io[(size_t)urow * SH + gcol];
    float cinB = io[(size_t)(CHB + urow) * SH + gcol];

    const int akb = wv * 256 + (lane >> 4) * 8;   // A-frag k offset
    bf16_t *curA = stA1, *nxtA = stA0;            // step0 writes stA1/stB1
    bf16_t *curB = stB1, *nxtB = stB0;

    // ---- step 0 (both chains): state zero -> rec = 0 ----
    {
        float zA = fminf(fmaxf(cinA, -15.f), 15.f);
        float zB = fminf(fmaxf(cinB, -15.f), 15.f);
        const float eA = __expf(2.0f * zA), eB = __expf(2.0f * zB);
        float snA = fminf(fmaxf(al * ((eA - 1.0f) / (eA + 1.0f)), -1.0f), 1.0f);
        float snB = fminf(fmaxf(al * ((eB - 1.0f) / (eB + 1.0f)), -1.0f), 1.0f);
        float pA = __shfl_xor(snA, 1);
        float pB = __shfl_xor(snB, 1);
        if ((lane & 1) == 0) {
            union { bf16_t b[2]; u32 u; } q;
            q.b[0] = (bf16_t)snA; q.b[1] = (bf16_t)pA;
            __hip_atomic_store((u32*)(curA + (size_t)urow * HID + gcol), q.u,
                               __ATOMIC_RELAXED, __HIP_MEMORY_SCOPE_AGENT);
            q.b[0] = (bf16_t)snB; q.b[1] = (bf16_t)pB;
            __hip_atomic_store((u32*)(curB + (size_t)urow * HID + gcol), q.u,
                               __ATOMIC_RELAXED, __HIP_MEMORY_SCOPE_AGENT);
        }
        io[(size_t)urow * SH + gcol] = snA;
        io[(size_t)(CHB + urow) * SH + gcol] = snB;
        s_oldA = snA; s_oldB = snB;
        cinA = io[(size_t)urow * SH + HID + gcol];
        cinB = io[(size_t)(CHB + urow) * SH + HID + gcol];
        __syncthreads();   // full drain of everyone's state stores
        if (tid == 0) {
            __hip_atomic_store(flags + (int)blockIdx.x, 1,
                               __ATOMIC_RELAXED, __HIP_MEMORY_SCOPE_AGENT);
            __hip_atomic_store(flags + 64 + (int)blockIdx.x, 1,
                               __ATOMIC_RELAXED, __HIP_MEMORY_SCOPE_AGENT);
        }
    }

#define SB __builtin_amdgcn_sched_barrier(0)
#define MF(u_, kf) \
        acc0 = __builtin_amdgcn_mfma_f32_16x16x32_bf16(u_.v, wf[kf],      acc0, 0, 0, 0); \
        acc1 = __builtin_amdgcn_mfma_f32_16x16x32_bf16(u_.v, wf[8 + kf],  acc1, 0, 0, 0); \
        acc2 = __builtin_amdgcn_mfma_f32_16x16x32_bf16(u_.v, wf[16 + kf], acc2, 0, 0, 0); \
        acc3 = __builtin_amdgcn_mfma_f32_16x16x32_bf16(u_.v, wf[24 + kf], acc3, 0, 0, 0);

    for (int t = 1; t < SEQLEN; ++t) {
        const int tn = (t < SEQLEN - 1) ? (t + 1) : t;

        // ================= PHASE A (batches 0-7) =================
        if (wv == 0) {
            int v;
            do {
                v = __hip_atomic_load(flags + (lane & 31),
                                      __ATOMIC_RELAXED, __HIP_MEMORY_SCOPE_AGENT);
            } while (__ballot(v < t) != 0ull);
        }
        SB; asm volatile("s_barrier" ::: "memory"); SB;
        {
            const bf16_t* ab = curA + (size_t)(lane & 7) * HID + akb;
            union uf { i32x4 i; bf16x8 v; } a0_, a1_, a2_, a3_, a4_, a5_, a6_, a7_;
            asm volatile("global_load_dwordx4 %0, %1, off sc0 sc1"            : "=v"(a0_.i) : "v"(ab) : "memory");
            asm volatile("global_load_dwordx4 %0, %1, off offset:64 sc0 sc1"  : "=v"(a1_.i) : "v"(ab) : "memory");
            asm volatile("global_load_dwordx4 %0, %1, off offset:128 sc0 sc1" : "=v"(a2_.i) : "v"(ab) : "memory");
            asm volatile("global_load_dwordx4 %0, %1, off offset:192 sc0 sc1" : "=v"(a3_.i) : "v"(ab) : "memory");
            asm volatile("global_load_dwordx4 %0, %1, off offset:256 sc0 sc1" : "=v"(a4_.i) : "v"(ab) : "memory");
            asm volatile("global_load_dwordx4 %0, %1, off offset:320 sc0 sc1" : "=v"(a5_.i) : "v"(ab) : "memory");
            asm volatile("global_load_dwordx4 %0, %1, off offset:384 sc0 sc1" : "=v"(a6_.i) : "v"(ab) : "memory");
            asm volatile("global_load_dwordx4 %0, %1, off offset:448 sc0 sc1" : "=v"(a7_.i) : "v"(ab) : "memory");
            float cinN = io[(size_t)urow * SH + (size_t)tn * HID + gcol];  // prefetch

            f32x4 acc0 = {0.f,0.f,0.f,0.f}, acc1 = {0.f,0.f,0.f,0.f};
            f32x4 acc2 = {0.f,0.f,0.f,0.f}, acc3 = {0.f,0.f,0.f,0.f};
            asm volatile("s_waitcnt vmcnt(5)" ::: "memory"); SB;
            MF(a0_, 0) MF(a1_, 1) MF(a2_, 2) MF(a3_, 3)
            asm volatile("s_waitcnt vmcnt(1)" ::: "memory"); SB;
            MF(a4_, 4) MF(a5_, 5) MF(a6_, 6) MF(a7_, 7)

            if (lane < 32) {
                const int r0 = (lane >> 4) * 4;
                const int cA = lane & 15;
#pragma unroll
                for (int r = 0; r < 4; ++r) {
                    red[wv][r0 + r][cA]      = acc0[r];
                    red[wv][r0 + r][16 + cA] = acc1[r];
                    red[wv][r0 + r][32 + cA] = acc2[r];
                    red[wv][r0 + r][48 + cA] = acc3[r];
                }
            }
            asm volatile("s_waitcnt lgkmcnt(0)" ::: "memory"); SB;
            asm volatile("s_barrier" ::: "memory"); SB;

            float rec = 0.f;
#pragma unroll
            for (int q = 0; q < 8; ++q) rec += red[q][urow][ucol];

            float z = fminf(fmaxf(cinA + rec, -15.f), 15.f);
            const float e = __expf(2.0f * z);
            const float tg = (e - 1.0f) / (e + 1.0f);
            float sn = fminf(fmaxf(s_oldA + al * (tg - s_oldA), -1.0f), 1.0f);

            float pp = __shfl_xor(sn, 1);
            if ((lane & 1) == 0) {
                union { bf16_t b[2]; u32 u; } q;
                q.b[0] = (bf16_t)sn; q.b[1] = (bf16_t)pp;
                __hip_atomic_store((u32*)(nxtA + (size_t)urow * HID + gcol), q.u,
                                   __ATOMIC_RELAXED, __HIP_MEMORY_SCOPE_AGENT);
            }
            asm volatile("s_waitcnt vmcnt(0)" ::: "memory"); SB;
            asm volatile("s_barrier" ::: "memory"); SB;
            if (t != SEQLEN - 1 && tid == 0)
                __hip_atomic_store(flags + (int)blockIdx.x, t + 1,
                                   __ATOMIC_RELAXED, __HIP_MEMORY_SCOPE_AGENT);
            io[(size_t)urow * SH + (size_t)t * HID + gcol] = sn;   // out of drain path
            s_oldA = sn; cinA = cinN;
            bf16_t* tmp = curA; curA = nxtA; nxtA = tmp;
        }

        // ================= PHASE B (batches 8-15) =================
        if (wv == 0) {
            int v;
            do {
                v = __hip_atomic_load(flags + 64 + (lane & 31),
                                      __ATOMIC_RELAXED, __HIP_MEMORY_SCOPE_AGENT);
            } while (__ballot(v < t) != 0ull);
        }
        SB; asm volatile("s_barrier" ::: "memory"); SB;
        {
            const bf16_t* ab = curB + (size_t)(lane & 7) * HID + akb;
            union uf { i32x4 i; bf16x8 v; } a0_, a1_, a2_, a3_, a4_, a5_, a6_, a7_;
            asm volatile("global_load_dwordx4 %0, %1, off sc0 sc1"            : "=v"(a0_.i) : "v"(ab) : "memory");
            asm volatile("global_load_dwordx4 %0, %1, off offset:64 sc0 sc1"  : "=v"(a1_.i) : "v"(ab) : "memory");
            asm volatile("global_load_dwordx4 %0, %1, off offset:128 sc0 sc1" : "=v"(a2_.i) : "v"(ab) : "memory");
            asm volatile("global_load_dwordx4 %0, %1, off offset:192 sc0 sc1" : "=v"(a3_.i) : "v"(ab) : "memory");
            asm volatile("global_load_dwordx4 %0, %1, off offset:256 sc0 sc1" : "=v"(a4_.i) : "v"(ab) : "memory");
            asm volatile("global_load_dwordx4 %0, %1, off offset:320 sc0 sc1" : "=v"(a5_.i) : "v"(ab) : "memory");
            asm volatile("global_load_dwordx4 %0, %1, off offset:384 sc0 sc1" : "=v"(a6_.i) : "v"(ab) : "memory");
            asm volatile("global_load_dwordx4 %0, %1, off offset:448 sc0 sc1" : "=v"(a7_.i) : "v"(ab) : "memory");
            float cinN = io[(size_t)(CHB + urow) * SH + (size_t)tn * HID + gcol];  // prefetch

            f32x4 acc0 = {0.f,0.f,0.f,0.f}, acc1 = {0.f,0.f,0.f,0.f};
            f32x4 acc2 = {0.f,0.f,0.f,0.f}, acc3 = {0.f,0.f,0.f,0.f};
            asm volatile("s_waitcnt vmcnt(5)" ::: "memory"); SB;
            MF(a0_, 0) MF(a1_, 1) MF(a2_, 2) MF(a3_, 3)
            asm volatile("s_waitcnt vmcnt(1)" ::: "memory"); SB;
            MF(a4_, 4) MF(a5_, 5) MF(a6_, 6) MF(a7_, 7)

            if (lane < 32) {
                const int r0 = (lane >> 4) * 4;
                const int cA = lane & 15;
#pragma unroll
                for (int r = 0; r < 4; ++r) {
                    red[wv][r0 + r][cA]      = acc0[r];
                    red[wv][r0 + r][16 + cA] = acc1[r];
                    red[wv][r0 + r][32 + cA] = acc2[r];
                    red[wv][r0 + r][48 + cA] = acc3[r];
                }
            }
            asm volatile("s_waitcnt lgkmcnt(0)" ::: "memory"); SB;
            asm volatile("s_barrier" ::: "memory"); SB;

            float rec = 0.f;
#pragma unroll
            for (int q = 0; q < 8; ++q) rec += red[q][urow][ucol];

            float z = fminf(fmaxf(cinB + rec, -15.f), 15.f);
            const float e = __expf(2.0f * z);
            const float tg = (e - 1.0f) / (e + 1.0f);
            float sn = fminf(fmaxf(s_oldB + al * (tg - s_oldB), -1.0f), 1.0f);

            float pp = __shfl_xor(sn, 1);
            if ((lane & 1) == 0) {
                union { bf16_t b[2]; u32 u; } q;
                q.b[0] = (bf16_t)sn; q.b[1] = (bf16_t)pp;
                __hip_atomic_store((u32*)(nxtB + (size_t)urow * HID + gcol), q.u,
                                   __ATOMIC_RELAXED, __HIP_MEMORY_SCOPE_AGENT);
            }
            asm volatile("s_waitcnt vmcnt(0)" ::: "memory"); SB;
            asm volatile("s_barrier" ::: "memory"); SB;
            if (t != SEQLEN - 1 && tid == 0)
                __hip_atomic_store(flags + 64 + (int)blockIdx.x, t + 1,
                                   __ATOMIC_RELAXED, __HIP_MEMORY_SCOPE_AGENT);
            io[(size_t)(CHB + urow) * SH + (size_t)t * HID + gcol] = sn;
            s_oldB = sn; cinB = cinN;
            bf16_t* tmp = curB; curB = nxtB; nxtB = tmp;
        }
    }
#undef MF
#undef SB
}

// ================= LayerNorm (in-place on d_out) =================
__global__ __launch_bounds__(256) void ln_kernel(
    float* __restrict__ io,
    const float* __restrict__ gamma,
    const float* __restrict__ beta)
{
    const size_t row = blockIdx.x;
    float* p = io + row * HID;
    const int tid = threadIdx.x;
    float4 v0 = *(const float4*)(p + tid * 4);
    float4 v1 = *(const float4*)(p + 1024 + tid * 4);
    float s  = v0.x + v0.y + v0.z + v0.w + v1.x + v1.y + v1.z + v1.w;
    float ss = v0.x * v0.x + v0.y * v0.y + v0.z * v0.z + v0.w * v0.w
             + v1.x * v1.x + v1.y * v1.y + v1.z * v1.z + v1.w * v1.w;
#pragma unroll
    for (int off = 32; off > 0; off >>= 1) {
        s  += __shfl_down(s, off, 64);
        ss += __shfl_down(ss, off, 64);
    }
    __shared__ float rs[4], rss[4];
    if ((tid & 63) == 0) { rs[tid >> 6] = s; rss[tid >> 6] = ss; }
    __syncthreads();
    s  = rs[0] + rs[1] + rs[2] + rs[3];
    ss = rss[0] + rss[1] + rss[2] + rss[3];
    const float mu = s * (1.f / HID);
    const float var = ss * (1.f / HID) - mu * mu;
    const float inv = rsqrtf(var + LN_EPS);
    const int c0 = tid * 4, c1 = 1024 + tid * 4;
    float4 g0 = *(const float4*)(gamma + c0);
    float4 g1 = *(const float4*)(gamma + c1);
    float4 b0 = *(const float4*)(beta + c0);
    float4 b1 = *(const float4*)(beta + c1);
    float4 o0, o1;
    o0.x = (v0.x - mu) * inv * g0.x + b0.x;
    o0.y = (v0.y - mu) * inv * g0.y + b0.y;
    o0.z = (v0.z - mu) * inv * g0.z + b0.z;
    o0.w = (v0.w - mu) * inv * g0.w + b0.w;
    o1.x = (v1.x - mu) * inv * g1.x + b1.x;
    o1.y = (v1.y - mu) * inv * g1.y + b1.y;
    o1.z = (v1.z - mu) * inv * g1.z + b1.z;
    o1.w = (v1.w - mu) * inv * g1.w + b1.w;
    *(float4*)(p + tid * 4) = o0;
    *(float4*)(p + 1024 + tid * 4) = o1;
}

extern "C" void kernel_launch(void* const* d_in, const int* in_sizes, int n_in,
                              void* d_out, int out_size, void* d_ws, size_t ws_size,
                              hipStream_t stream)
{
    const float* x     = (const float*)d_in[0];
    const float* Wi    = (const float*)d_in[1];
    const float* bias  = (const float*)d_in[2];
    const float* Wr    = (const float*)d_in[3];
    const float* mask  = (const float*)d_in[4];
    const float* tau   = (const float*)d_in[5];
    const float* gamma = (const float*)d_in[6];
    const float* beta  = (const float*)d_in[7];
    float* out = (float*)d_out;

    bf16_t* stA0 = (bf16_t*)d_ws;
    bf16_t* stA1 = stA0 + (size_t)CHB * HID;
    bf16_t* stB0 = stA1 + (size_t)CHB * HID;
    bf16_t* stB1 = stB0 + (size_t)CHB * HID;
    int* flags   = (int*)(stB1 + (size_t)CHB * HID);

    // 1) input projection -> d_out rows hold inp[b,t,:] (fp32); also zeroes flags
    gemm_proj<<<dim3(16, 64), 256, 0, stream>>>(x, Wi, bias, out, flags);
    // 2) persistent dual-chain recurrence
    recurrent<<<NBLK, RTHREADS, 0, stream>>>(Wr, mask, tau, out,
                                             stA0, stA1, stB0, stB1, flags);
    // 3) layernorm in-place
    ln_kernel<<<MTOT, 256, 0, stream>>>(out, gamma, beta);
}